// Round 2
// baseline (2772.259 us; speedup 1.0000x reference)
//
#include <hip/hip_runtime.h>
#include <cmath>

#define HEADS 4
#define HID 32
#define IN_DIM 128
#define OUT_DIM 64
#define D1 (HEADS*HID)   /* 128 */
#define NEG_SLOPE 0.2f
#define BN_EPS 1e-5f

// ---- monotone float<->uint encoding for atomicMax on floats ----
__device__ __forceinline__ unsigned enc_f(float x){
  unsigned u = __float_as_uint(x);
  return (u & 0x80000000u) ? ~u : (u | 0x80000000u);
}
__device__ __forceinline__ float dec_f(unsigned u){
  unsigned v = (u & 0x80000000u) ? (u & 0x7FFFFFFFu) : ~u;
  return __uint_as_float(v);
}

// ---- K1: h1 = x @ W1 (no bias), fused per-head attention dots ----
// block = 128 threads, 4 nodes/block
__global__ void gemm1(const float* __restrict__ x, const float* __restrict__ W,
                      const float* __restrict__ a_s, const float* __restrict__ a_d,
                      float* __restrict__ h, float* __restrict__ asn,
                      float* __restrict__ adn, int n)
{
  __shared__ float xs[4][IN_DIM];
  int base = blockIdx.x * 4;
  int tid = threadIdx.x;   // 0..127 = output column
  #pragma unroll
  for (int i = 0; i < 4; ++i) {
    int node = base + i;
    xs[i][tid] = (node < n) ? x[(size_t)node*IN_DIM + tid] : 0.f;
  }
  __syncthreads();
  float acc[4] = {0.f,0.f,0.f,0.f};
  for (int k = 0; k < IN_DIM; ++k) {
    float w = W[k*D1 + tid];
    #pragma unroll
    for (int i = 0; i < 4; ++i) acc[i] = fmaf(xs[i][k], w, acc[i]);
  }
  int head = tid >> 5, d = tid & 31;
  float vs = a_s[head*HID + d], vd = a_d[head*HID + d];
  #pragma unroll
  for (int i = 0; i < 4; ++i) {
    int node = base + i;
    if (node >= n) break;
    h[(size_t)node*D1 + tid] = acc[i];
    float ps = acc[i]*vs, pd = acc[i]*vd;
    #pragma unroll
    for (int m = 16; m >= 1; m >>= 1) { ps += __shfl_xor(ps, m); pd += __shfl_xor(pd, m); }
    if (d == 0) { asn[node*HEADS + head] = ps; adn[node*HEADS + head] = pd; }
  }
}

// ---- K2: per-edge (all 4 heads) alpha = leaky_relu(as[src]+ad[dst]); segment max ----
__global__ void edge_alpha1(const int* __restrict__ ei, int E, int n,
                            const float4* __restrict__ as4, const float4* __restrict__ ad4,
                            float4* __restrict__ alpha4, unsigned* __restrict__ menc)
{
  int e = blockIdx.x*blockDim.x + threadIdx.x;
  if (e >= E + n) return;
  int s_, d_;
  if (e < E) { s_ = ei[e]; d_ = ei[E + e]; } else { s_ = d_ = e - E; }
  float4 a = as4[s_], b = ad4[d_];
  float4 al;
  al.x = a.x + b.x; al.x = al.x > 0.f ? al.x : NEG_SLOPE*al.x;
  al.y = a.y + b.y; al.y = al.y > 0.f ? al.y : NEG_SLOPE*al.y;
  al.z = a.z + b.z; al.z = al.z > 0.f ? al.z : NEG_SLOPE*al.z;
  al.w = a.w + b.w; al.w = al.w > 0.f ? al.w : NEG_SLOPE*al.w;
  alpha4[e] = al;
  unsigned* mp = &menc[d_*HEADS];
  atomicMax(mp+0, enc_f(al.x));
  atomicMax(mp+1, enc_f(al.y));
  atomicMax(mp+2, enc_f(al.z));
  atomicMax(mp+3, enc_f(al.w));
}

// ---- K3: e = exp(alpha - m[dst]); segment sum ----
__global__ void edge_exp1(const int* __restrict__ ei, int E, int n,
                          const uint4* __restrict__ menc4,
                          float4* __restrict__ alpha4, float* __restrict__ ssum)
{
  int e = blockIdx.x*blockDim.x + threadIdx.x;
  if (e >= E + n) return;
  int d_ = (e < E) ? ei[E + e] : (e - E);
  uint4 mu = menc4[d_];
  float4 al = alpha4[e];
  float4 ev;
  ev.x = __expf(al.x - dec_f(mu.x));
  ev.y = __expf(al.y - dec_f(mu.y));
  ev.z = __expf(al.z - dec_f(mu.z));
  ev.w = __expf(al.w - dec_f(mu.w));
  alpha4[e] = ev;
  float* sp = &ssum[d_*HEADS];
  atomicAdd(sp+0, ev.x);
  atomicAdd(sp+1, ev.y);
  atomicAdd(sp+2, ev.z);
  atomicAdd(sp+3, ev.w);
}

// ---- K4: agg[dst] += h[src] * coef  (thread per (edge, 4cols)) ----
__global__ void edge_agg1(const int* __restrict__ ei, int E, int n,
                          const float* __restrict__ evals, const float* __restrict__ ssum,
                          const float4* __restrict__ h4, float* __restrict__ agg)
{
  long long t = (long long)blockIdx.x*blockDim.x + threadIdx.x;
  if (t >= (long long)(E + n)*32) return;
  int e = (int)(t >> 5), c = (int)(t & 31);   // c: which float4 of the 128-wide row
  int s_, d_;
  if (e < E) { s_ = ei[e]; d_ = ei[E + e]; } else { s_ = d_ = e - E; }
  int head = c >> 3;
  float coef = evals[e*HEADS + head] / (ssum[d_*HEADS + head] + 1e-16f);
  float4 hv = h4[(size_t)s_*32 + c];
  float* ap = &agg[(size_t)d_*D1 + c*4];
  atomicAdd(ap+0, hv.x * coef);
  atomicAdd(ap+1, hv.y * coef);
  atomicAdd(ap+2, hv.z * coef);
  atomicAdd(ap+3, hv.w * coef);
}

// ---- BN + ELU (in place), layer 1 ----
__global__ void bn_elu(float* __restrict__ zio, const float* __restrict__ bias,
                       const float* __restrict__ g, const float* __restrict__ b,
                       const float* __restrict__ m, const float* __restrict__ v,
                       int total, int mask)
{
  int i = blockIdx.x*blockDim.x + threadIdx.x;
  if (i >= total) return;
  int j = i & mask;
  float val = zio[i] + bias[j];
  val = (val - m[j]) * rsqrtf(v[j] + BN_EPS) * g[j] + b[j];
  zio[i] = val > 0.f ? val : expm1f(val);
}

// ---- K6: h2 = z1 @ W2, fused attention dots (heads=1) ----
__global__ void gemm2(const float* __restrict__ z, const float* __restrict__ W,
                      const float* __restrict__ a_s, const float* __restrict__ a_d,
                      float* __restrict__ h2, float* __restrict__ as2,
                      float* __restrict__ ad2, int n)
{
  __shared__ float zs[4][D1];
  int base = blockIdx.x * 4;
  int tid = threadIdx.x;
  for (int idx = tid; idx < 4*D1; idx += 256) {
    int i = idx >> 7, k = idx & 127;
    int node = base + i;
    zs[i][k] = (node < n) ? z[(size_t)node*D1 + k] : 0.f;
  }
  __syncthreads();
  int i = tid >> 6;
  int j = tid & 63;
  int node = base + i;
  float acc = 0.f;
  for (int k = 0; k < D1; ++k) acc = fmaf(zs[i][k], W[k*OUT_DIM + j], acc);
  if (node < n) {
    h2[(size_t)node*OUT_DIM + j] = acc;
    float ps = acc * a_s[j], pd = acc * a_d[j];
    #pragma unroll
    for (int m = 32; m >= 1; m >>= 1) { ps += __shfl_xor(ps, m); pd += __shfl_xor(pd, m); }
    if (j == 0) { as2[node] = ps; ad2[node] = pd; }
  }
}

// ---- K7/K8: layer-2 edge softmax (1 head) ----
__global__ void edge_alpha2(const int* __restrict__ ei, int E, int n,
                            const float* __restrict__ as2, const float* __restrict__ ad2,
                            float* __restrict__ alpha, unsigned* __restrict__ menc)
{
  int e = blockIdx.x*blockDim.x + threadIdx.x;
  if (e >= E + n) return;
  int s_, d_;
  if (e < E) { s_ = ei[e]; d_ = ei[E + e]; } else { s_ = d_ = e - E; }
  float al = as2[s_] + ad2[d_];
  al = al > 0.f ? al : NEG_SLOPE*al;
  alpha[e] = al;
  atomicMax(&menc[d_], enc_f(al));
}

__global__ void edge_exp2(const int* __restrict__ ei, int E, int n,
                          const unsigned* __restrict__ menc,
                          float* __restrict__ alpha, float* __restrict__ ssum)
{
  int e = blockIdx.x*blockDim.x + threadIdx.x;
  if (e >= E + n) return;
  int d_ = (e < E) ? ei[E + e] : (e - E);
  float ev = __expf(alpha[e] - dec_f(menc[d_]));
  alpha[e] = ev;
  atomicAdd(&ssum[d_], ev);
}

// ---- K9: layer-2 aggregation (thread per (edge, 4cols)) ----
__global__ void edge_agg2(const int* __restrict__ ei, int E, int n,
                          const float* __restrict__ evals, const float* __restrict__ ssum,
                          const float4* __restrict__ h4, float* __restrict__ agg)
{
  long long t = (long long)blockIdx.x*blockDim.x + threadIdx.x;
  if (t >= (long long)(E + n)*16) return;
  int e = (int)(t >> 4), c = (int)(t & 15);
  int s_, d_;
  if (e < E) { s_ = ei[e]; d_ = ei[E + e]; } else { s_ = d_ = e - E; }
  float coef = evals[e] / (ssum[d_] + 1e-16f);
  float4 hv = h4[(size_t)s_*16 + c];
  float* ap = &agg[(size_t)d_*OUT_DIM + c*4];
  atomicAdd(ap+0, hv.x * coef);
  atomicAdd(ap+1, hv.y * coef);
  atomicAdd(ap+2, hv.z * coef);
  atomicAdd(ap+3, hv.w * coef);
}

// ---- K10: fused BN2+ELU + per-node pair-MLP precompute ----
// u[n] = z2[n] @ hW1[0:64,:],  v[n] = z2[n] @ hW1[64:128,:]
// block = 256 = 4 waves; wave per node; lane = output col
__global__ void uv_prep(const float* __restrict__ agg2, const float* __restrict__ bias,
                        const float* __restrict__ g, const float* __restrict__ b,
                        const float* __restrict__ bm, const float* __restrict__ bv,
                        const float* __restrict__ hW1,
                        float* __restrict__ u, float* __restrict__ vout, int n)
{
  __shared__ float2 w1s[OUT_DIM][OUT_DIM];   // (top[k][c], bot[k][c]) -> 32 KiB
  int tid = threadIdx.x;
  for (int idx = tid; idx < OUT_DIM*OUT_DIM; idx += 256) {
    int k = idx >> 6, c = idx & 63;
    w1s[k][c] = make_float2(hW1[k*OUT_DIM + c], hW1[(OUT_DIM + k)*OUT_DIM + c]);
  }
  __syncthreads();
  int wave = tid >> 6, lane = tid & 63;
  int node = blockIdx.x*4 + wave;
  if (node >= n) return;
  float val = agg2[(size_t)node*OUT_DIM + lane] + bias[lane];
  val = (val - bm[lane]) * rsqrtf(bv[lane] + BN_EPS) * g[lane] + b[lane];
  float z = val > 0.f ? val : expm1f(val);
  float ua = 0.f, va = 0.f;
  #pragma unroll
  for (int k = 0; k < OUT_DIM; ++k) {
    float zk = __shfl(z, k);
    float2 w = w1s[k][lane];
    ua = fmaf(zk, w.x, ua);
    va = fmaf(zk, w.y, va);
  }
  u[(size_t)node*OUT_DIM + lane]    = ua;
  vout[(size_t)node*OUT_DIM + lane] = va;
}

// ---- K11: pair scoring: sigmoid( ELU(u[s]+v[d]+hb1) . hW2 + hb2 ) ----
// 16 lanes x float4 per pair
__global__ void pair_score(const int* __restrict__ src, const int* __restrict__ dst,
                           const float4* __restrict__ u4, const float4* __restrict__ v4,
                           const float4* __restrict__ hb1, const float4* __restrict__ hW2,
                           const float* __restrict__ hb2, float* __restrict__ out, int P)
{
  int t = blockIdx.x*blockDim.x + threadIdx.x;
  int p = t >> 4, sub = t & 15;
  if (p >= P) return;
  int sp = src[p], dp = dst[p];
  float4 a = u4[(size_t)sp*16 + sub];
  float4 b = v4[(size_t)dp*16 + sub];
  float4 hb = hb1[sub];
  float4 w2 = hW2[sub];
  float h0 = a.x + b.x + hb.x; h0 = h0 > 0.f ? h0 : expm1f(h0);
  float h1 = a.y + b.y + hb.y; h1 = h1 > 0.f ? h1 : expm1f(h1);
  float h2 = a.z + b.z + hb.z; h2 = h2 > 0.f ? h2 : expm1f(h2);
  float h3 = a.w + b.w + hb.w; h3 = h3 > 0.f ? h3 : expm1f(h3);
  float pl = h0*w2.x + h1*w2.y + h2*w2.z + h3*w2.w;
  pl += __shfl_xor(pl, 1);
  pl += __shfl_xor(pl, 2);
  pl += __shfl_xor(pl, 4);
  pl += __shfl_xor(pl, 8);
  if (sub == 0) out[p] = 1.f / (1.f + __expf(-(pl + hb2[0])));
}

extern "C" void kernel_launch(void* const* d_in, const int* in_sizes, int n_in,
                              void* d_out, int out_size, void* d_ws, size_t ws_size,
                              hipStream_t stream)
{
  const float* x    = (const float*)d_in[0];
  const int*   ei   = (const int*)d_in[1];
  const int*   src  = (const int*)d_in[2];
  const int*   dst  = (const int*)d_in[3];
  const float* W1   = (const float*)d_in[4];
  const float* a1s  = (const float*)d_in[5];
  const float* a1d  = (const float*)d_in[6];
  const float* b1   = (const float*)d_in[7];
  const float* bn1g = (const float*)d_in[8];
  const float* bn1b = (const float*)d_in[9];
  const float* bn1m = (const float*)d_in[10];
  const float* bn1v = (const float*)d_in[11];
  const float* W2   = (const float*)d_in[12];
  const float* a2s  = (const float*)d_in[13];
  const float* a2d  = (const float*)d_in[14];
  const float* b2   = (const float*)d_in[15];
  const float* bn2g = (const float*)d_in[16];
  const float* bn2b = (const float*)d_in[17];
  const float* bn2m = (const float*)d_in[18];
  const float* bn2v = (const float*)d_in[19];
  const float* hW1  = (const float*)d_in[20];
  const float* hb1  = (const float*)d_in[21];
  const float* hW2  = (const float*)d_in[22];
  const float* hb2  = (const float*)d_in[23];

  const int N  = in_sizes[0] / IN_DIM;
  const int E  = in_sizes[1] / 2;
  const int P  = in_sizes[2];
  const int Ep = E + N;

  // ---- workspace layout (floats), with aliasing ----
  float* ws = (float*)d_ws;
  float* h1     = ws;                          // N*128  (later: h2 N*64, then u/v N*64 each)
  float* agg1   = h1   + (size_t)N*D1;         // N*128  (later: agg2 = N*64)
  float* alpha1 = agg1 + (size_t)N*D1;         // Ep*4   (later: alpha2 = Ep)
  float* as1    = alpha1 + (size_t)Ep*HEADS;   // N*4
  float* ad1    = as1 + (size_t)N*HEADS;       // N*4
  unsigned* m1  = (unsigned*)(ad1 + (size_t)N*HEADS); // N*4
  float* s1     = (float*)(m1 + (size_t)N*HEADS);     // N*4
  float* as2    = s1 + (size_t)N*HEADS;        // N
  float* ad2    = as2 + N;                     // N
  unsigned* m2  = (unsigned*)(ad2 + N);        // N
  float* s2     = (float*)(m2 + N);            // N
  float* h2     = h1;        // reuse (h1 dead after gemm2 input read? no: h1 dead after edge_agg1)
  float* alpha2 = alpha1;    // reuse
  float* agg2   = agg1;      // reuse
  float* u      = h1;                          // N*64 (h2 dead after edge_agg2)
  float* v      = h1 + (size_t)N*OUT_DIM;      // N*64

  // ---- layer 1 ----
  hipMemsetAsync(agg1, 0, (size_t)N*D1*sizeof(float), stream);
  hipMemsetAsync(m1,   0, (size_t)N*HEADS*sizeof(unsigned), stream);
  hipMemsetAsync(s1,   0, (size_t)N*HEADS*sizeof(float), stream);
  hipMemsetAsync(m2,   0, (size_t)N*sizeof(unsigned), stream);
  hipMemsetAsync(s2,   0, (size_t)N*sizeof(float), stream);

  gemm1<<<(N + 3)/4, 128, 0, stream>>>(x, W1, a1s, a1d, h1, as1, ad1, N);

  {
    int blocks = (Ep + 255) / 256;
    edge_alpha1<<<blocks, 256, 0, stream>>>(ei, E, N, (const float4*)as1,
                                            (const float4*)ad1, (float4*)alpha1, m1);
    edge_exp1  <<<blocks, 256, 0, stream>>>(ei, E, N, (const uint4*)m1,
                                            (float4*)alpha1, s1);
  }
  {
    long long total = (long long)Ep * 32;
    int blocks = (int)((total + 255) / 256);
    edge_agg1<<<blocks, 256, 0, stream>>>(ei, E, N, alpha1, s1, (const float4*)h1, agg1);
  }
  bn_elu<<<(N*D1 + 255)/256, 256, 0, stream>>>(agg1, b1, bn1g, bn1b, bn1m, bn1v,
                                               N*D1, D1 - 1);

  // ---- layer 2 ----
  gemm2<<<(N + 3)/4, 256, 0, stream>>>(agg1, W2, a2s, a2d, h2, as2, ad2, N);

  hipMemsetAsync(agg2, 0, (size_t)N*OUT_DIM*sizeof(float), stream);  // after gemm2 read z1

  {
    int blocks = (Ep + 255) / 256;
    edge_alpha2<<<blocks, 256, 0, stream>>>(ei, E, N, as2, ad2, alpha2, m2);
    edge_exp2  <<<blocks, 256, 0, stream>>>(ei, E, N, m2, alpha2, s2);
  }
  {
    long long total = (long long)Ep * 16;
    int blocks = (int)((total + 255) / 256);
    edge_agg2<<<blocks, 256, 0, stream>>>(ei, E, N, alpha2, s2, (const float4*)h2, agg2);
  }

  // fused BN2 + ELU + u/v precompute (u,v overwrite h1/h2 region — h2 is dead now)
  uv_prep<<<(N + 3)/4, 256, 0, stream>>>(agg2, b2, bn2g, bn2b, bn2m, bn2v, hW1, u, v, N);

  // ---- pair scoring ----
  {
    long long total = (long long)P * 16;
    int blocks = (int)((total + 255) / 256);
    pair_score<<<blocks, 256, 0, stream>>>(src, dst, (const float4*)u, (const float4*)v,
                                           (const float4*)hb1, (const float4*)hW2,
                                           hb2, (float*)d_out, P);
  }
}

// Round 3
// 455.293 us; speedup vs baseline: 6.0889x; 6.0889x over previous
//
#include <hip/hip_runtime.h>
#include <cmath>

#define HEADS 4
#define HID 32
#define IN_DIM 128
#define OUT_DIM 64
#define D1 (HEADS*HID)   /* 128 */
#define NEG_SLOPE 0.2f
#define BN_EPS 1e-5f

// ================= CSR build (dst-sorted incoming-edge lists) =================

__global__ void deg_count(const int* __restrict__ ei, int E, unsigned* __restrict__ deg)
{
  int e = blockIdx.x*blockDim.x + threadIdx.x;
  if (e < E) atomicAdd(&deg[ei[E + e]], 1u);
}

// per-256-tile sums of (deg[i]+1)   (+1 = self loop)
__global__ void tile_sum(const unsigned* __restrict__ deg, unsigned* __restrict__ part, int n)
{
  __shared__ unsigned red[256];
  int tid = threadIdx.x;
  int i = blockIdx.x*256 + tid;
  red[tid] = (i < n) ? deg[i] + 1u : 0u;
  __syncthreads();
  for (int o = 128; o >= 1; o >>= 1) {
    if (tid < o) red[tid] += red[tid + o];
    __syncthreads();
  }
  if (tid == 0) part[blockIdx.x] = red[0];
}

// single-block exclusive scan of tile partials; writes offs[n] = total
__global__ void part_scan(unsigned* __restrict__ part, unsigned* __restrict__ offs_n, int ntiles)
{
  __shared__ unsigned sh[256];
  int tid = threadIdx.x;
  unsigned carry = 0;
  for (int base = 0; base < ntiles; base += 256) {
    int i = base + tid;
    unsigned v = (i < ntiles) ? part[i] : 0u;
    sh[tid] = v;
    __syncthreads();
    for (int o = 1; o < 256; o <<= 1) {
      unsigned t = (tid >= o) ? sh[tid - o] : 0u;
      __syncthreads();
      sh[tid] += t;
      __syncthreads();
    }
    unsigned incl = sh[tid];
    if (i < ntiles) part[i] = carry + incl - v;   // exclusive tile prefix
    unsigned tot = sh[255];
    __syncthreads();
    carry += tot;
  }
  if (tid == 0) offs_n[0] = carry;
}

// per-tile exclusive scan -> node offsets
__global__ void tile_scan_write(const unsigned* __restrict__ deg, const unsigned* __restrict__ part,
                                unsigned* __restrict__ offs, int n)
{
  __shared__ unsigned sh[256];
  int tid = threadIdx.x;
  int i = blockIdx.x*256 + tid;
  unsigned v = (i < n) ? deg[i] + 1u : 0u;
  sh[tid] = v;
  __syncthreads();
  for (int o = 1; o < 256; o <<= 1) {
    unsigned t = (tid >= o) ? sh[tid - o] : 0u;
    __syncthreads();
    sh[tid] += t;
    __syncthreads();
  }
  if (i < n) offs[i] = part[blockIdx.x] + sh[tid] - v;
}

__global__ void csr_fill(const int* __restrict__ ei, int E, int n,
                         const unsigned* __restrict__ offs, unsigned* __restrict__ cursor,
                         int* __restrict__ csr)
{
  int t = blockIdx.x*blockDim.x + threadIdx.x;
  if (t >= E + n) return;
  int s_, d_;
  if (t < E) { s_ = ei[t]; d_ = ei[E + t]; } else { s_ = d_ = t - E; }
  unsigned pos = offs[d_] + atomicAdd(&cursor[d_], 1u);
  csr[pos] = s_;
}

// ================= layer GEMMs (with fused attention dots) =================

// h1 = x @ W1; block = 128 threads, 4 nodes/block
__global__ void gemm1(const float* __restrict__ x, const float* __restrict__ W,
                      const float* __restrict__ a_s, const float* __restrict__ a_d,
                      float* __restrict__ h, float* __restrict__ asn,
                      float* __restrict__ adn, int n)
{
  __shared__ float xs[4][IN_DIM];
  int base = blockIdx.x * 4;
  int tid = threadIdx.x;
  #pragma unroll
  for (int i = 0; i < 4; ++i) {
    int node = base + i;
    xs[i][tid] = (node < n) ? x[(size_t)node*IN_DIM + tid] : 0.f;
  }
  __syncthreads();
  float acc[4] = {0.f,0.f,0.f,0.f};
  for (int k = 0; k < IN_DIM; ++k) {
    float w = W[k*D1 + tid];
    #pragma unroll
    for (int i = 0; i < 4; ++i) acc[i] = fmaf(xs[i][k], w, acc[i]);
  }
  int head = tid >> 5, d = tid & 31;
  float vs = a_s[head*HID + d], vd = a_d[head*HID + d];
  #pragma unroll
  for (int i = 0; i < 4; ++i) {
    int node = base + i;
    if (node >= n) break;
    h[(size_t)node*D1 + tid] = acc[i];
    float ps = acc[i]*vs, pd = acc[i]*vd;
    #pragma unroll
    for (int m = 16; m >= 1; m >>= 1) { ps += __shfl_xor(ps, m); pd += __shfl_xor(pd, m); }
    if (d == 0) { asn[node*HEADS + head] = ps; adn[node*HEADS + head] = pd; }
  }
}

// h2 = z1 @ W2; block = 256 = 4 nodes x 64 cols
__global__ void gemm2(const float* __restrict__ z, const float* __restrict__ W,
                      const float* __restrict__ a_s, const float* __restrict__ a_d,
                      float* __restrict__ h2, float* __restrict__ as2,
                      float* __restrict__ ad2, int n)
{
  __shared__ float zs[4][D1];
  int base = blockIdx.x * 4;
  int tid = threadIdx.x;
  for (int idx = tid; idx < 4*D1; idx += 256) {
    int i = idx >> 7, k = idx & 127;
    int node = base + i;
    zs[i][k] = (node < n) ? z[(size_t)node*D1 + k] : 0.f;
  }
  __syncthreads();
  int i = tid >> 6, j = tid & 63;
  int node = base + i;
  float acc = 0.f;
  for (int k = 0; k < D1; ++k) acc = fmaf(zs[i][k], W[k*OUT_DIM + j], acc);
  if (node < n) {
    h2[(size_t)node*OUT_DIM + j] = acc;
    float ps = acc * a_s[j], pd = acc * a_d[j];
    #pragma unroll
    for (int m = 32; m >= 1; m >>= 1) { ps += __shfl_xor(ps, m); pd += __shfl_xor(pd, m); }
    if (j == 0) { as2[node] = ps; ad2[node] = pd; }
  }
}

// ========== fused per-node online-softmax + gather aggregation ==========

// layer 1: 4 heads. Wave per node; lane owns cols [2*lane, 2*lane+1]; head = lane>>4.
__global__ void node_agg1(const int* __restrict__ csr, const unsigned* __restrict__ offs,
                          const float4* __restrict__ as4, const float4* __restrict__ ad4,
                          const float2* __restrict__ hp, float2* __restrict__ aggp, int n)
{
  int lane = threadIdx.x & 63;
  int node = blockIdx.x*4 + (threadIdx.x >> 6);
  if (node >= n) return;
  unsigned beg = offs[node], end = offs[node+1];
  float4 adv = ad4[node];
  int head = lane >> 4;
  float ax = 0.f, ay = 0.f;
  float4 m = make_float4(-3e38f,-3e38f,-3e38f,-3e38f);
  float4 s = make_float4(0.f,0.f,0.f,0.f);
  for (unsigned c = beg; c < end; c += 64) {
    unsigned j = c + lane;
    bool valid = (j < end);
    int sj = valid ? csr[j] : 0;
    float4 av = as4[sj];
    float4 al;
    al.x = av.x + adv.x; al.x = al.x > 0.f ? al.x : NEG_SLOPE*al.x;
    al.y = av.y + adv.y; al.y = al.y > 0.f ? al.y : NEG_SLOPE*al.y;
    al.z = av.z + adv.z; al.z = al.z > 0.f ? al.z : NEG_SLOPE*al.z;
    al.w = av.w + adv.w; al.w = al.w > 0.f ? al.w : NEG_SLOPE*al.w;
    if (!valid) { al.x = al.y = al.z = al.w = -3e38f; }
    float4 cm = al;
    #pragma unroll
    for (int o = 32; o >= 1; o >>= 1) {
      cm.x = fmaxf(cm.x, __shfl_xor(cm.x, o));
      cm.y = fmaxf(cm.y, __shfl_xor(cm.y, o));
      cm.z = fmaxf(cm.z, __shfl_xor(cm.z, o));
      cm.w = fmaxf(cm.w, __shfl_xor(cm.w, o));
    }
    float4 mn = make_float4(fmaxf(m.x,cm.x), fmaxf(m.y,cm.y), fmaxf(m.z,cm.z), fmaxf(m.w,cm.w));
    float4 r  = make_float4(__expf(m.x-mn.x), __expf(m.y-mn.y), __expf(m.z-mn.z), __expf(m.w-mn.w));
    float4 w;
    w.x = valid ? __expf(al.x - mn.x) : 0.f;
    w.y = valid ? __expf(al.y - mn.y) : 0.f;
    w.z = valid ? __expf(al.z - mn.z) : 0.f;
    w.w = valid ? __expf(al.w - mn.w) : 0.f;
    float4 t = w;
    #pragma unroll
    for (int o = 32; o >= 1; o >>= 1) {
      t.x += __shfl_xor(t.x, o);
      t.y += __shfl_xor(t.y, o);
      t.z += __shfl_xor(t.z, o);
      t.w += __shfl_xor(t.w, o);
    }
    s.x = s.x*r.x + t.x; s.y = s.y*r.y + t.y; s.z = s.z*r.z + t.z; s.w = s.w*r.w + t.w;
    m = mn;
    float rh = head==0 ? r.x : head==1 ? r.y : head==2 ? r.z : r.w;
    ax *= rh; ay *= rh;
    int cd = (int)min(64u, end - c);
    for (int j2 = 0; j2 < cd; ++j2) {
      int sv = __shfl(sj, j2);
      float wx = __shfl(w.x, j2), wy = __shfl(w.y, j2);
      float wz = __shfl(w.z, j2), ww = __shfl(w.w, j2);
      float wv = head==0 ? wx : head==1 ? wy : head==2 ? wz : ww;
      float2 hv = hp[(size_t)sv*64 + lane];
      ax = fmaf(hv.x, wv, ax);
      ay = fmaf(hv.y, wv, ay);
    }
  }
  float sh = head==0 ? s.x : head==1 ? s.y : head==2 ? s.z : s.w;
  float inv = 1.f / (sh + 1e-16f);
  aggp[(size_t)node*64 + lane] = make_float2(ax*inv, ay*inv);
}

// layer 2: 1 head, 64 cols; wave per node, lane = col
__global__ void node_agg2(const int* __restrict__ csr, const unsigned* __restrict__ offs,
                          const float* __restrict__ as2, const float* __restrict__ ad2,
                          const float* __restrict__ hp, float* __restrict__ aggp, int n)
{
  int lane = threadIdx.x & 63;
  int node = blockIdx.x*4 + (threadIdx.x >> 6);
  if (node >= n) return;
  unsigned beg = offs[node], end = offs[node+1];
  float adv = ad2[node];
  float acc = 0.f, m = -3e38f, s = 0.f;
  for (unsigned c = beg; c < end; c += 64) {
    unsigned j = c + lane;
    bool valid = (j < end);
    int sj = valid ? csr[j] : 0;
    float al = as2[sj] + adv;
    al = al > 0.f ? al : NEG_SLOPE*al;
    if (!valid) al = -3e38f;
    float cm = al;
    #pragma unroll
    for (int o = 32; o >= 1; o >>= 1) cm = fmaxf(cm, __shfl_xor(cm, o));
    float mn = fmaxf(m, cm);
    float r  = __expf(m - mn);
    float w  = valid ? __expf(al - mn) : 0.f;
    float t  = w;
    #pragma unroll
    for (int o = 32; o >= 1; o >>= 1) t += __shfl_xor(t, o);
    s = s*r + t;
    m = mn;
    acc *= r;
    int cd = (int)min(64u, end - c);
    for (int j2 = 0; j2 < cd; ++j2) {
      int sv = __shfl(sj, j2);
      float wv = __shfl(w, j2);
      acc = fmaf(hp[(size_t)sv*64 + lane], wv, acc);
    }
  }
  aggp[(size_t)node*64 + lane] = acc / (s + 1e-16f);
}

// ---- BN + ELU (in place), layer 1 ----
__global__ void bn_elu(float* __restrict__ zio, const float* __restrict__ bias,
                       const float* __restrict__ g, const float* __restrict__ b,
                       const float* __restrict__ m, const float* __restrict__ v,
                       int total, int mask)
{
  int i = blockIdx.x*blockDim.x + threadIdx.x;
  if (i >= total) return;
  int j = i & mask;
  float val = zio[i] + bias[j];
  val = (val - m[j]) * rsqrtf(v[j] + BN_EPS) * g[j] + b[j];
  zio[i] = val > 0.f ? val : expm1f(val);
}

// ---- fused BN2+ELU + per-node pair-MLP precompute ----
__global__ void uv_prep(const float* __restrict__ agg2, const float* __restrict__ bias,
                        const float* __restrict__ g, const float* __restrict__ b,
                        const float* __restrict__ bm, const float* __restrict__ bv,
                        const float* __restrict__ hW1,
                        float* __restrict__ u, float* __restrict__ vout, int n)
{
  __shared__ float2 w1s[OUT_DIM][OUT_DIM];   // (top[k][c], bot[k][c]) -> 32 KiB
  int tid = threadIdx.x;
  for (int idx = tid; idx < OUT_DIM*OUT_DIM; idx += 256) {
    int k = idx >> 6, c = idx & 63;
    w1s[k][c] = make_float2(hW1[k*OUT_DIM + c], hW1[(OUT_DIM + k)*OUT_DIM + c]);
  }
  __syncthreads();
  int wave = tid >> 6, lane = tid & 63;
  int node = blockIdx.x*4 + wave;
  if (node >= n) return;
  float val = agg2[(size_t)node*OUT_DIM + lane] + bias[lane];
  val = (val - bm[lane]) * rsqrtf(bv[lane] + BN_EPS) * g[lane] + b[lane];
  float z = val > 0.f ? val : expm1f(val);
  float ua = 0.f, va = 0.f;
  #pragma unroll
  for (int k = 0; k < OUT_DIM; ++k) {
    float zk = __shfl(z, k);
    float2 w = w1s[k][lane];
    ua = fmaf(zk, w.x, ua);
    va = fmaf(zk, w.y, va);
  }
  u[(size_t)node*OUT_DIM + lane]    = ua;
  vout[(size_t)node*OUT_DIM + lane] = va;
}

// ---- pair scoring: sigmoid( ELU(u[s]+v[d]+hb1) . hW2 + hb2 ) ----
__global__ void pair_score(const int* __restrict__ src, const int* __restrict__ dst,
                           const float4* __restrict__ u4, const float4* __restrict__ v4,
                           const float4* __restrict__ hb1, const float4* __restrict__ hW2,
                           const float* __restrict__ hb2, float* __restrict__ out, int P)
{
  int t = blockIdx.x*blockDim.x + threadIdx.x;
  int p = t >> 4, sub = t & 15;
  if (p >= P) return;
  int sp = src[p], dp = dst[p];
  float4 a = u4[(size_t)sp*16 + sub];
  float4 b = v4[(size_t)dp*16 + sub];
  float4 hb = hb1[sub];
  float4 w2 = hW2[sub];
  float h0 = a.x + b.x + hb.x; h0 = h0 > 0.f ? h0 : expm1f(h0);
  float h1 = a.y + b.y + hb.y; h1 = h1 > 0.f ? h1 : expm1f(h1);
  float h2 = a.z + b.z + hb.z; h2 = h2 > 0.f ? h2 : expm1f(h2);
  float h3 = a.w + b.w + hb.w; h3 = h3 > 0.f ? h3 : expm1f(h3);
  float pl = h0*w2.x + h1*w2.y + h2*w2.z + h3*w2.w;
  pl += __shfl_xor(pl, 1);
  pl += __shfl_xor(pl, 2);
  pl += __shfl_xor(pl, 4);
  pl += __shfl_xor(pl, 8);
  if (sub == 0) out[p] = 1.f / (1.f + __expf(-(pl + hb2[0])));
}

extern "C" void kernel_launch(void* const* d_in, const int* in_sizes, int n_in,
                              void* d_out, int out_size, void* d_ws, size_t ws_size,
                              hipStream_t stream)
{
  const float* x    = (const float*)d_in[0];
  const int*   ei   = (const int*)d_in[1];
  const int*   src  = (const int*)d_in[2];
  const int*   dst  = (const int*)d_in[3];
  const float* W1   = (const float*)d_in[4];
  const float* a1s  = (const float*)d_in[5];
  const float* a1d  = (const float*)d_in[6];
  const float* b1   = (const float*)d_in[7];
  const float* bn1g = (const float*)d_in[8];
  const float* bn1b = (const float*)d_in[9];
  const float* bn1m = (const float*)d_in[10];
  const float* bn1v = (const float*)d_in[11];
  const float* W2   = (const float*)d_in[12];
  const float* a2s  = (const float*)d_in[13];
  const float* a2d  = (const float*)d_in[14];
  const float* b2   = (const float*)d_in[15];
  const float* bn2g = (const float*)d_in[16];
  const float* bn2b = (const float*)d_in[17];
  const float* bn2m = (const float*)d_in[18];
  const float* bn2v = (const float*)d_in[19];
  const float* hW1  = (const float*)d_in[20];
  const float* hb1  = (const float*)d_in[21];
  const float* hW2  = (const float*)d_in[22];
  const float* hb2  = (const float*)d_in[23];

  const int N  = in_sizes[0] / IN_DIM;
  const int E  = in_sizes[1] / 2;
  const int P  = in_sizes[2];
  const int Ep = E + N;
  const int ntiles = (N + 255) / 256;

  // ---- workspace layout ----
  float* ws = (float*)d_ws;
  float* h1   = ws;                          // N*128  (later h2 N*64, then u/v)
  float* agg1 = h1 + (size_t)N*D1;           // N*128  (later agg2 N*64)
  float* as1  = agg1 + (size_t)N*D1;         // N*4
  float* ad1  = as1 + (size_t)N*HEADS;       // N*4
  float* as2  = ad1 + (size_t)N*HEADS;       // N
  float* ad2  = as2 + N;                     // N
  unsigned* deg    = (unsigned*)(ad2 + N);   // N
  unsigned* offs   = deg + N;                // N+1
  unsigned* cursor = offs + N + 1;           // N
  unsigned* part   = cursor + N;             // ntiles
  int* csr         = (int*)(part + ntiles);  // Ep
  float* h2   = h1;
  float* agg2 = agg1;
  float* u    = h1;                          // N*64
  float* v    = h1 + (size_t)N*OUT_DIM;      // N*64

  // ---- CSR build ----
  hipMemsetAsync(deg,    0, (size_t)N*sizeof(unsigned), stream);
  hipMemsetAsync(cursor, 0, (size_t)N*sizeof(unsigned), stream);
  deg_count<<<(E + 255)/256, 256, 0, stream>>>(ei, E, deg);
  tile_sum<<<ntiles, 256, 0, stream>>>(deg, part, N);
  part_scan<<<1, 256, 0, stream>>>(part, offs + N, ntiles);
  tile_scan_write<<<ntiles, 256, 0, stream>>>(deg, part, offs, N);
  csr_fill<<<(Ep + 255)/256, 256, 0, stream>>>(ei, E, N, offs, cursor, csr);

  // ---- layer 1 ----
  gemm1<<<(N + 3)/4, 128, 0, stream>>>(x, W1, a1s, a1d, h1, as1, ad1, N);
  node_agg1<<<(N + 3)/4, 256, 0, stream>>>(csr, offs, (const float4*)as1, (const float4*)ad1,
                                           (const float2*)h1, (float2*)agg1, N);
  bn_elu<<<(N*D1 + 255)/256, 256, 0, stream>>>(agg1, b1, bn1g, bn1b, bn1m, bn1v,
                                               N*D1, D1 - 1);

  // ---- layer 2 ----
  gemm2<<<(N + 3)/4, 256, 0, stream>>>(agg1, W2, a2s, a2d, h2, as2, ad2, N);
  node_agg2<<<(N + 3)/4, 256, 0, stream>>>(csr, offs, as2, ad2, h2, agg2, N);

  // fused BN2 + ELU + u/v precompute (u,v overwrite h1/h2 region — h2 dead now)
  uv_prep<<<(N + 3)/4, 256, 0, stream>>>(agg2, b2, bn2g, bn2b, bn2m, bn2v, hW1, u, v, N);

  // ---- pair scoring ----
  {
    long long total = (long long)P * 16;
    int blocks = (int)((total + 255) / 256);
    pair_score<<<blocks, 256, 0, stream>>>(src, dst, (const float4*)u, (const float4*)v,
                                           (const float4*)hb1, (const float4*)hW2,
                                           hb2, (float*)d_out, P);
  }
}